// Round 4
// baseline (1523.362 us; speedup 1.0000x reference)
//
#include <hip/hip_runtime.h>
#include <math.h>
#include <float.h>

// ---- problem constants (N=1, C=1, 256x256, sigma scalar) ----
constexpr int IMG  = 256;            // H = W
constexpr int PADR = 21;             // p//2 + w//2 = 3 + 18
constexpr int PDIM = IMG + 2*PADR;   // 298
constexpr int XDIM = PDIM - 7 + 1;   // 292  (unfold spatial dim)
constexpr int LTOT = XDIM * XDIM;    // 85264
constexpr int WSZ  = 37;             // search window
constexpr int INC  = 18;             // WSZ/2
constexpr int ST   = 4;              // stride
constexpr int GDIM = 64;             // query grid per dim (256/4)
constexpr int NBLK = GDIM * GDIM;    // 4096
constexpr int PS   = 7;              // patch size
constexpr int PP   = 49;             // patch pixels
constexpr int MM1  = 18;
constexpr int MM2  = 55;
constexpr int RG   = 43;             // search region = 2*INC + PS
constexpr int NOFF = WSZ * WSZ;      // 1369
constexpr int UCAP = (NOFF + 63) / 64;  // 22 dist values cached per lane

// ---------------- reflect pad: src (IMG x IMG) -> dst (PDIM x PDIM) ----------
__global__ void pad_reflect(const float* __restrict__ src, float* __restrict__ dst)
{
    int idx = blockIdx.x * 256 + threadIdx.x;
    if (idx >= PDIM * PDIM) return;
    int y = idx / PDIM, x = idx % PDIM;
    int oy = y - PADR; oy = (oy < 0) ? -oy : ((oy >= IMG) ? 2*(IMG-1) - oy : oy);
    int ox = x - PADR; ox = (ox < 0) ? -ox : ((ox >= IMG) ? 2*(IMG-1) - ox : ox);
    dst[idx] = src[oy * IMG + ox];
}

// ---------------- block matching: one workgroup per query block -------------
// Top-m selection entirely on wave 0 in registers (no barriers in the loop).
__global__ __launch_bounds__(256) void block_match(const float* __restrict__ pad,
                                                   int* __restrict__ pos, int m)
{
    __shared__ float reg[RG][RG + 1];
    __shared__ float dist[NOFF];

    const int gi = blockIdx.y, gj = blockIdx.x;
    const int tid = threadIdx.x;
    const int r0 = ST * gi, c0 = ST * gj;

    for (int t = tid; t < RG * RG; t += 256) {
        int r = t / RG, c = t % RG;
        reg[r][c] = pad[(r0 + r) * PDIM + (c0 + c)];
    }
    __syncthreads();

    float q[PP];
#pragma unroll
    for (int i = 0; i < PS; i++)
#pragma unroll
        for (int j = 0; j < PS; j++)
            q[i * PS + j] = reg[INC + i][INC + j];

    for (int o = tid; o < NOFF; o += 256) {
        int oi = o / WSZ, oj = o % WSZ;
        float s = 0.f;
#pragma unroll
        for (int i = 0; i < PS; i++)
#pragma unroll
            for (int j = 0; j < PS; j++) {
                float d = reg[oi + i][oj + j] - q[i * PS + j];
                s += d * d;
            }
        dist[o] = (o == INC * WSZ + INC) ? -1.0f : s;   // self match sentinel
    }
    __syncthreads();

    if (tid >= 64) return;        // selection runs on wave 0 only
    const int lane = tid;

    float dv[UCAP];
#pragma unroll
    for (int u = 0; u < UCAP; u++) {
        int o = lane + (u << 6);
        dv[u] = (o < NOFF) ? dist[o] : FLT_MAX;
    }

    const int blk = gi * GDIM + gj;
    for (int sel = 0; sel < m; sel++) {
        float bv = dv[0]; int bo = lane;
#pragma unroll
        for (int u = 1; u < UCAP; u++) {
            int o = lane + (u << 6);
            if (dv[u] < bv) { bv = dv[u]; bo = o; }
        }
#pragma unroll
        for (int d = 1; d < 64; d <<= 1) {
            float ov = __shfl_xor(bv, d);
            int   oo = __shfl_xor(bo, d);
            if (ov < bv || (ov == bv && oo < bo)) { bv = ov; bo = oo; }
        }
        if (lane == 0) {
            int oi = bo / WSZ, oj = bo % WSZ;
            pos[blk * m + sel] = (oi + ST * gi) * XDIM + (oj + ST * gj);
        }
#pragma unroll
        for (int u = 0; u < UCAP; u++)
            if (bo == lane + (u << 6)) dv[u] = FLT_MAX;
    }
}

// ---------------- denoise + scatter: one workgroup per group ----------------
// M = Gram(S) (+ c*I if ADDC). Inversion: symmetric sweep operator on wave 0,
// column-per-lane in registers (A -> -A^{-1}), broadcast via v_readlane.
// theta = I - c*Minv; Xh = Y - c*(Minv Y); w_k = 1/rowsum(theta^2).
// Scatter into 49 per-patch-pixel planes (low per-address contention);
// dispatch order permuted so concurrent blocks don't share cache lines.
template<int M_, bool ADDC>
__global__ __launch_bounds__(256) void denoise_scatter(
    const float* __restrict__ padY, const float* __restrict__ padS,
    const int* __restrict__ pos, const float* __restrict__ sigma_p,
    float* __restrict__ Xsum, float* __restrict__ Wacc)
{
    constexpr int MP = (M_ + 4) & ~3;        // Msh row stride (mult of 4): 56 / 20
    constexpr int SS = 52;                   // Ssh row stride (13*16B, zero-padded)
    constexpr int YS = 60;                   // Yt  row stride (15*16B)

    __shared__ __align__(16) float Ssh[M_ * SS];
    __shared__ __align__(16) float Yt [PP * YS];   // Yt[qq][k] = Y patch k, pixel qq
    __shared__ __align__(16) float Msh[M_ * MP];
    __shared__ float wsh[M_];
    __shared__ int   posh[M_];

    const int tid = threadIdx.x;
    const int blk = (blockIdx.x * 1031) & (NBLK - 1);   // bijective decorrelation
    const float sg = *sigma_p;
    const float c  = (float)PP * sg * sg;

    if (tid < M_) posh[tid] = pos[blk * M_ + tid];
    __syncthreads();

    // gather A: Ssh row-major (stride-1 LDS writes), cols 49..51 zeroed
    for (int t = tid; t < M_ * SS; t += 256) {
        int k = t / SS, qq = t - k * SS;
        float v = 0.f;
        if (qq < PP) {
            int p_ = posh[k];
            int a = p_ / XDIM, b = p_ - (p_ / XDIM) * XDIM;
            v = padS[(a + qq / PS) * PDIM + (b + qq % PS)];
        }
        Ssh[t] = v;
    }
    // gather B: Yt transposed (k fastest -> stride-1 LDS writes)
    for (int t = tid; t < PP * M_; t += 256) {
        int qq = t / M_, k = t - qq * M_;
        int p_ = posh[k];
        int a = p_ / XDIM, b = p_ - (p_ / XDIM) * XDIM;
        Yt[qq * YS + k] = padY[(a + qq / PS) * PDIM + (b + qq % PS)];
    }
    __syncthreads();

    // Gram, lower triangle only, float4 over q
    for (int t = tid; t < M_ * M_; t += 256) {
        int i = t / M_, j = t - i * M_;
        if (j > i) continue;
        const float4* Si = (const float4*)&Ssh[i * SS];
        const float4* Sj = (const float4*)&Ssh[j * SS];
        float acc = 0.f;
#pragma unroll
        for (int cch = 0; cch < SS / 4; cch++) {
            float4 a4 = Si[cch], b4 = Sj[cch];
            acc += a4.x * b4.x + a4.y * b4.y + a4.z * b4.z + a4.w * b4.w;
        }
        if (ADDC && i == j) acc += c;
        Msh[i * MP + j] = acc;
    }
    __syncthreads();

    // ---- symmetric sweep inversion on wave 0 (register columns) ----
    if (tid < 64) {
        const int j = (tid < M_) ? tid : (M_ - 1);   // clamp extra lanes
        float col[M_];
#pragma unroll
        for (int i = 0; i < M_; i++)
            col[i] = Msh[(i >= j) ? (i * MP + j) : (j * MP + i)];

#pragma unroll
        for (int k = 0; k < M_; k++) {
            float d = __int_as_float(__builtin_amdgcn_readlane(__float_as_int(col[k]), k));
            d = (fabsf(d) > 1e-30f) ? d : 1e-30f;
            float dinv = 1.0f / d;
            float cks = col[k];
            float f  = (j == k) ? (1.0f - dinv) : (cks * dinv);
            float fn = -f;
#pragma unroll
            for (int i = 0; i < M_; i++) {
                if (i == k) continue;
                float aik = __int_as_float(__builtin_amdgcn_readlane(__float_as_int(cks), i));
                col[i] = fmaf(aik, fn, col[i]);
            }
            col[k] = (j == k) ? (-dinv) : (cks * dinv);
        }
        // now col = column j of -M^{-1}
        if (tid < M_) {
            float s = 0.f;
#pragma unroll
            for (int i = 0; i < M_; i++) {
                float th = fmaf(c, col[i], (i == j) ? 1.f : 0.f);  // I - c*Minv
                s = fmaf(th, th, s);
            }
            wsh[j] = 1.0f / s;
#pragma unroll
            for (int i = 0; i < M_; i++)
                Msh[i * MP + j] = -col[i];                          // Minv (full)
        }
    }
    __syncthreads();

    // ---- Z = Minv*Y fused with weighted scatter into 49 planes ----
    for (int t = tid; t < M_ * PP; t += 256) {
        int k = t / PP, qq = t - k * PP;
        const float4* Mi = (const float4*)&Msh[k * MP];
        const float4* Yq = (const float4*)&Yt [qq * YS];
        float z = 0.f;
#pragma unroll
        for (int cch = 0; cch < M_ / 4; cch++) {
            float4 a4 = Mi[cch], b4 = Yq[cch];
            z += a4.x * b4.x + a4.y * b4.y + a4.z * b4.z + a4.w * b4.w;
        }
#pragma unroll
        for (int jj = (M_ / 4) * 4; jj < M_; jj++)
            z += Msh[k * MP + jj] * Yt[qq * YS + jj];
        float xh = Yt[qq * YS + k] - c * z;
        atomicAdd(&Xsum[qq * LTOT + posh[k]], xh * wsh[k]);
    }
    for (int t = tid; t < M_; t += 256)
        atomicAdd(&Wacc[posh[t]], wsh[t]);
}

// ---------------- fold (49-tap over planes) + normalize + crop --------------
__global__ void fold_norm(const float* __restrict__ Xsum, const float* __restrict__ Wacc,
                          float* __restrict__ out)
{
    int idx = blockIdx.x * 256 + threadIdx.x;
    if (idx >= IMG * IMG) return;
    int y0 = idx / IMG, x0 = idx % IMG;
    int y = y0 + PADR, x = x0 + PADR;
    float num = 0.f, den = 0.f;
#pragma unroll
    for (int i = 0; i < PS; i++)
#pragma unroll
        for (int j = 0; j < PS; j++) {
            int a = y - i, b = x - j;
            num += Xsum[(i * PS + j) * LTOT + a * XDIM + b];
            den += Wacc[a * XDIM + b];
        }
    out[idx] = num / den;
}

extern "C" void kernel_launch(void* const* d_in, const int* in_sizes, int n_in,
                              void* d_out, int out_size, void* d_ws, size_t ws_size,
                              hipStream_t stream)
{
    const float* input = (const float*)d_in[0];
    const float* sigma = (const float*)d_in[1];
    float* out = (float*)d_out;

    char* ws = (char*)d_ws;
    float* padY = (float*)ws; ws += (size_t)PDIM * PDIM * 4;
    float* padX = (float*)ws; ws += (size_t)PDIM * PDIM * 4;
    float* den1 = (float*)ws; ws += (size_t)IMG * IMG * 4;
    int*   pos  = (int*)ws;   ws += (size_t)NBLK * MM2 * 4;
    float* Xsum = (float*)ws; ws += (size_t)PP * LTOT * 4;
    float* Wacc = (float*)ws; ws += (size_t)LTOT * 4;

    const int padBlocks = (PDIM * PDIM + 255) / 256;
    const int imgBlocks = (IMG * IMG + 255) / 256;

    // ---- stage 1 ----
    hipMemsetAsync(Xsum, 0, (size_t)PP * LTOT * 4, stream);
    hipMemsetAsync(Wacc, 0, (size_t)LTOT * 4, stream);
    pad_reflect<<<padBlocks, 256, 0, stream>>>(input, padY);
    block_match<<<dim3(GDIM, GDIM), 256, 0, stream>>>(padY, pos, MM1);
    denoise_scatter<MM1, false><<<NBLK, 256, 0, stream>>>(padY, padY, pos, sigma, Xsum, Wacc);
    fold_norm<<<imgBlocks, 256, 0, stream>>>(Xsum, Wacc, den1);

    // ---- stage 2 ----
    pad_reflect<<<padBlocks, 256, 0, stream>>>(den1, padX);
    hipMemsetAsync(Xsum, 0, (size_t)PP * LTOT * 4, stream);
    hipMemsetAsync(Wacc, 0, (size_t)LTOT * 4, stream);
    block_match<<<dim3(GDIM, GDIM), 256, 0, stream>>>(padX, pos, MM2);
    denoise_scatter<MM2, true><<<NBLK, 256, 0, stream>>>(padY, padX, pos, sigma, Xsum, Wacc);
    fold_norm<<<imgBlocks, 256, 0, stream>>>(Xsum, Wacc, out);
}

// Round 5
// 1504.042 us; speedup vs baseline: 1.0128x; 1.0128x over previous
//
#include <hip/hip_runtime.h>
#include <math.h>
#include <float.h>

// ---- problem constants (N=1, C=1, 256x256, sigma scalar) ----
constexpr int IMG  = 256;            // H = W
constexpr int PADR = 21;             // p//2 + w//2 = 3 + 18
constexpr int PDIM = IMG + 2*PADR;   // 298
constexpr int XDIM = PDIM - 7 + 1;   // 292  (unfold spatial dim)
constexpr int LTOT = XDIM * XDIM;    // 85264
constexpr int WSZ  = 37;             // search window
constexpr int INC  = 18;             // WSZ/2
constexpr int ST   = 4;              // stride
constexpr int GDIM = 64;             // query grid per dim (256/4)
constexpr int NBLK = GDIM * GDIM;    // 4096
constexpr int PS   = 7;              // patch size
constexpr int PP   = 49;             // patch pixels
constexpr int MM1  = 18;
constexpr int MM2  = 55;
constexpr int RG   = 43;             // search region = 2*INC + PS
constexpr int NOFF = WSZ * WSZ;      // 1369
constexpr int UCAP = (NOFF + 63) / 64;  // 22 dist values cached per lane

// ---------------- reflect pad: src (IMG x IMG) -> dst (PDIM x PDIM) ----------
__global__ void pad_reflect(const float* __restrict__ src, float* __restrict__ dst)
{
    int idx = blockIdx.x * 256 + threadIdx.x;
    if (idx >= PDIM * PDIM) return;
    int y = idx / PDIM, x = idx % PDIM;
    int oy = y - PADR; oy = (oy < 0) ? -oy : ((oy >= IMG) ? 2*(IMG-1) - oy : oy);
    int ox = x - PADR; ox = (ox < 0) ? -ox : ((ox >= IMG) ? 2*(IMG-1) - ox : ox);
    dst[idx] = src[oy * IMG + ox];
}

// ---------------- block matching: one workgroup per query block -------------
// Top-m selection entirely on wave 0 in registers (no barriers in the loop).
__global__ __launch_bounds__(256) void block_match(const float* __restrict__ pad,
                                                   int* __restrict__ pos, int m)
{
    __shared__ float reg[RG][RG + 1];
    __shared__ float dist[NOFF];

    const int gi = blockIdx.y, gj = blockIdx.x;
    const int tid = threadIdx.x;
    const int r0 = ST * gi, c0 = ST * gj;

    for (int t = tid; t < RG * RG; t += 256) {
        int r = t / RG, c = t % RG;
        reg[r][c] = pad[(r0 + r) * PDIM + (c0 + c)];
    }
    __syncthreads();

    float q[PP];
#pragma unroll
    for (int i = 0; i < PS; i++)
#pragma unroll
        for (int j = 0; j < PS; j++)
            q[i * PS + j] = reg[INC + i][INC + j];

    for (int o = tid; o < NOFF; o += 256) {
        int oi = o / WSZ, oj = o % WSZ;
        float s = 0.f;
#pragma unroll
        for (int i = 0; i < PS; i++)
#pragma unroll
            for (int j = 0; j < PS; j++) {
                float d = reg[oi + i][oj + j] - q[i * PS + j];
                s += d * d;
            }
        dist[o] = (o == INC * WSZ + INC) ? -1.0f : s;   // self match sentinel
    }
    __syncthreads();

    if (tid >= 64) return;        // selection runs on wave 0 only
    const int lane = tid;

    float dv[UCAP];
#pragma unroll
    for (int u = 0; u < UCAP; u++) {
        int o = lane + (u << 6);
        dv[u] = (o < NOFF) ? dist[o] : FLT_MAX;
    }

    const int blk = gi * GDIM + gj;
    for (int sel = 0; sel < m; sel++) {
        float bv = dv[0]; int bo = lane;
#pragma unroll
        for (int u = 1; u < UCAP; u++) {
            int o = lane + (u << 6);
            if (dv[u] < bv) { bv = dv[u]; bo = o; }
        }
#pragma unroll
        for (int d = 1; d < 64; d <<= 1) {
            float ov = __shfl_xor(bv, d);
            int   oo = __shfl_xor(bo, d);
            if (ov < bv || (ov == bv && oo < bo)) { bv = ov; bo = oo; }
        }
        if (lane == 0) {
            int oi = bo / WSZ, oj = bo % WSZ;
            pos[blk * m + sel] = (oi + ST * gi) * XDIM + (oj + ST * gj);
        }
#pragma unroll
        for (int u = 0; u < UCAP; u++)
            if (bo == lane + (u << 6)) dv[u] = FLT_MAX;
    }
}

// ---------------- denoise + scatter: one workgroup per group ----------------
// M = Gram(S) (+ c*I if ADDC). Inversion: symmetric sweep operator on wave 0,
// column-per-lane in registers (A -> -A^{-1}), broadcast via v_readlane.
// theta = I - c*Minv; Xh = Y - c*(Minv Y); w_k = 1/rowsum(theta^2).
// Scatter into 49 per-patch-pixel planes, SEQUENTIAL block order (neighboring
// concurrent blocks write overlapping lines -> L2 absorbs atomic RMW traffic).
template<int M_, bool ADDC>
__global__ __launch_bounds__(256) void denoise_scatter(
    const float* __restrict__ padY, const float* __restrict__ padS,
    const int* __restrict__ pos, const float* __restrict__ sigma_p,
    float* __restrict__ Xsum, float* __restrict__ Wacc)
{
    constexpr int MP = (M_ + 4) & ~3;        // Msh row stride (mult of 4): 56 / 20
    constexpr int SS = 52;                   // Ssh row stride (13*16B, zero-padded)
    constexpr int YS = 60;                   // Yt  row stride (15*16B)

    __shared__ __align__(16) float Ssh[M_ * SS];
    __shared__ __align__(16) float Yt [PP * YS];   // Yt[qq][k] = Y patch k, pixel qq
    __shared__ __align__(16) float Msh[M_ * MP];
    __shared__ float wsh[M_];
    __shared__ int   posh[M_];

    const int tid = threadIdx.x;
    const int blk = blockIdx.x;
    const float sg = *sigma_p;
    const float c  = (float)PP * sg * sg;

    if (tid < M_) posh[tid] = pos[blk * M_ + tid];
    __syncthreads();

    // gather A: Ssh row-major (stride-1 LDS writes), cols 49..51 zeroed
    for (int t = tid; t < M_ * SS; t += 256) {
        int k = t / SS, qq = t - k * SS;
        float v = 0.f;
        if (qq < PP) {
            int p_ = posh[k];
            int a = p_ / XDIM, b = p_ - (p_ / XDIM) * XDIM;
            v = padS[(a + qq / PS) * PDIM + (b + qq % PS)];
        }
        Ssh[t] = v;
    }
    // gather B: Yt transposed (k fastest -> stride-1 LDS writes)
    for (int t = tid; t < PP * M_; t += 256) {
        int qq = t / M_, k = t - qq * M_;
        int p_ = posh[k];
        int a = p_ / XDIM, b = p_ - (p_ / XDIM) * XDIM;
        Yt[qq * YS + k] = padY[(a + qq / PS) * PDIM + (b + qq % PS)];
    }
    __syncthreads();

    // Gram, lower triangle only, float4 over q
    for (int t = tid; t < M_ * M_; t += 256) {
        int i = t / M_, j = t - i * M_;
        if (j > i) continue;
        const float4* Si = (const float4*)&Ssh[i * SS];
        const float4* Sj = (const float4*)&Ssh[j * SS];
        float acc = 0.f;
#pragma unroll
        for (int cch = 0; cch < SS / 4; cch++) {
            float4 a4 = Si[cch], b4 = Sj[cch];
            acc += a4.x * b4.x + a4.y * b4.y + a4.z * b4.z + a4.w * b4.w;
        }
        if (ADDC && i == j) acc += c;
        Msh[i * MP + j] = acc;
    }
    __syncthreads();

    // ---- symmetric sweep inversion on wave 0 (register columns) ----
    if (tid < 64) {
        const int j = (tid < M_) ? tid : (M_ - 1);   // clamp extra lanes
        float col[M_];
#pragma unroll
        for (int i = 0; i < M_; i++)
            col[i] = Msh[(i >= j) ? (i * MP + j) : (j * MP + i)];

#pragma unroll
        for (int k = 0; k < M_; k++) {
            float d = __int_as_float(__builtin_amdgcn_readlane(__float_as_int(col[k]), k));
            d = (fabsf(d) > 1e-30f) ? d : 1e-30f;
            float dinv = 1.0f / d;
            float cks = col[k];
            float f  = (j == k) ? (1.0f - dinv) : (cks * dinv);
            float fn = -f;
#pragma unroll
            for (int i = 0; i < M_; i++) {
                if (i == k) continue;
                float aik = __int_as_float(__builtin_amdgcn_readlane(__float_as_int(cks), i));
                col[i] = fmaf(aik, fn, col[i]);
            }
            col[k] = (j == k) ? (-dinv) : (cks * dinv);
        }
        // now col = column j of -M^{-1}
        if (tid < M_) {
            float s = 0.f;
#pragma unroll
            for (int i = 0; i < M_; i++) {
                float th = fmaf(c, col[i], (i == j) ? 1.f : 0.f);  // I - c*Minv
                s = fmaf(th, th, s);
            }
            wsh[j] = 1.0f / s;
#pragma unroll
            for (int i = 0; i < M_; i++)
                Msh[i * MP + j] = -col[i];                          // Minv (full)
        }
    }
    __syncthreads();

    // ---- Z = Minv*Y fused with weighted scatter into 49 planes ----
    for (int t = tid; t < M_ * PP; t += 256) {
        int k = t / PP, qq = t - k * PP;
        const float4* Mi = (const float4*)&Msh[k * MP];
        const float4* Yq = (const float4*)&Yt [qq * YS];
        float z = 0.f;
#pragma unroll
        for (int cch = 0; cch < M_ / 4; cch++) {
            float4 a4 = Mi[cch], b4 = Yq[cch];
            z += a4.x * b4.x + a4.y * b4.y + a4.z * b4.z + a4.w * b4.w;
        }
#pragma unroll
        for (int jj = (M_ / 4) * 4; jj < M_; jj++)
            z += Msh[k * MP + jj] * Yt[qq * YS + jj];
        float xh = Yt[qq * YS + k] - c * z;
        atomicAdd(&Xsum[qq * LTOT + posh[k]], xh * wsh[k]);
    }
    for (int t = tid; t < M_; t += 256)
        atomicAdd(&Wacc[posh[t]], wsh[t]);
}

// ---------------- fold (49-tap over planes) + normalize + crop --------------
__global__ void fold_norm(const float* __restrict__ Xsum, const float* __restrict__ Wacc,
                          float* __restrict__ out)
{
    int idx = blockIdx.x * 256 + threadIdx.x;
    if (idx >= IMG * IMG) return;
    int y0 = idx / IMG, x0 = idx % IMG;
    int y = y0 + PADR, x = x0 + PADR;
    float num = 0.f, den = 0.f;
#pragma unroll
    for (int i = 0; i < PS; i++)
#pragma unroll
        for (int j = 0; j < PS; j++) {
            int a = y - i, b = x - j;
            num += Xsum[(i * PS + j) * LTOT + a * XDIM + b];
            den += Wacc[a * XDIM + b];
        }
    out[idx] = num / den;
}

extern "C" void kernel_launch(void* const* d_in, const int* in_sizes, int n_in,
                              void* d_out, int out_size, void* d_ws, size_t ws_size,
                              hipStream_t stream)
{
    const float* input = (const float*)d_in[0];
    const float* sigma = (const float*)d_in[1];
    float* out = (float*)d_out;

    char* ws = (char*)d_ws;
    float* padY = (float*)ws; ws += (size_t)PDIM * PDIM * 4;
    float* padX = (float*)ws; ws += (size_t)PDIM * PDIM * 4;
    float* den1 = (float*)ws; ws += (size_t)IMG * IMG * 4;
    int*   pos  = (int*)ws;   ws += (size_t)NBLK * MM2 * 4;
    float* Xsum = (float*)ws; ws += (size_t)PP * LTOT * 4;
    float* Wacc = (float*)ws; ws += (size_t)LTOT * 4;

    const int padBlocks = (PDIM * PDIM + 255) / 256;
    const int imgBlocks = (IMG * IMG + 255) / 256;

    // ---- stage 1 ----
    hipMemsetAsync(Xsum, 0, (size_t)PP * LTOT * 4, stream);
    hipMemsetAsync(Wacc, 0, (size_t)LTOT * 4, stream);
    pad_reflect<<<padBlocks, 256, 0, stream>>>(input, padY);
    block_match<<<dim3(GDIM, GDIM), 256, 0, stream>>>(padY, pos, MM1);
    denoise_scatter<MM1, false><<<NBLK, 256, 0, stream>>>(padY, padY, pos, sigma, Xsum, Wacc);
    fold_norm<<<imgBlocks, 256, 0, stream>>>(Xsum, Wacc, den1);

    // ---- stage 2 ----
    pad_reflect<<<padBlocks, 256, 0, stream>>>(den1, padX);
    hipMemsetAsync(Xsum, 0, (size_t)PP * LTOT * 4, stream);
    hipMemsetAsync(Wacc, 0, (size_t)LTOT * 4, stream);
    block_match<<<dim3(GDIM, GDIM), 256, 0, stream>>>(padX, pos, MM2);
    denoise_scatter<MM2, true><<<NBLK, 256, 0, stream>>>(padY, padX, pos, sigma, Xsum, Wacc);
    fold_norm<<<imgBlocks, 256, 0, stream>>>(Xsum, Wacc, out);
}

// Round 6
// 1305.495 us; speedup vs baseline: 1.1669x; 1.1521x over previous
//
#include <hip/hip_runtime.h>
#include <math.h>
#include <float.h>

// ---- problem constants (N=1, C=1, 256x256, sigma scalar) ----
constexpr int IMG  = 256;            // H = W
constexpr int PADR = 21;             // p//2 + w//2 = 3 + 18
constexpr int PDIM = IMG + 2*PADR;   // 298
constexpr int XDIM = PDIM - 7 + 1;   // 292  (unfold spatial dim)
constexpr int LTOT = XDIM * XDIM;    // 85264
constexpr int WSZ  = 37;             // search window
constexpr int INC  = 18;             // WSZ/2
constexpr int ST   = 4;              // stride
constexpr int GDIM = 64;             // query grid per dim (256/4)
constexpr int NBLK = GDIM * GDIM;    // 4096
constexpr int PS   = 7;              // patch size
constexpr int PP   = 49;             // patch pixels
constexpr int MM1  = 18;
constexpr int MM2  = 55;
constexpr int RG   = 43;             // search region = 2*INC + PS
constexpr int NOFF = WSZ * WSZ;      // 1369
constexpr int UCAP = (NOFF + 63) / 64;  // 22 dist values cached per lane
constexpr int TDIM = 43;             // per-group output footprint (37 + 7 - 1)
constexpr int TSZ  = TDIM * TDIM;    // 1849
constexpr int SLABSTRIDE = 2 * TSZ;  // num + weight channels per group

// ---------------- reflect pad: src (IMG x IMG) -> dst (PDIM x PDIM) ----------
__global__ void pad_reflect(const float* __restrict__ src, float* __restrict__ dst)
{
    int idx = blockIdx.x * 256 + threadIdx.x;
    if (idx >= PDIM * PDIM) return;
    int y = idx / PDIM, x = idx % PDIM;
    int oy = y - PADR; oy = (oy < 0) ? -oy : ((oy >= IMG) ? 2*(IMG-1) - oy : oy);
    int ox = x - PADR; ox = (ox < 0) ? -ox : ((ox >= IMG) ? 2*(IMG-1) - ox : ox);
    dst[idx] = src[oy * IMG + ox];
}

// ---------------- block matching: one workgroup per query block -------------
__global__ __launch_bounds__(256) void block_match(const float* __restrict__ pad,
                                                   int* __restrict__ pos, int m)
{
    __shared__ float reg[RG][RG + 1];
    __shared__ float dist[NOFF];

    const int gi = blockIdx.y, gj = blockIdx.x;
    const int tid = threadIdx.x;
    const int r0 = ST * gi, c0 = ST * gj;

    for (int t = tid; t < RG * RG; t += 256) {
        int r = t / RG, c = t % RG;
        reg[r][c] = pad[(r0 + r) * PDIM + (c0 + c)];
    }
    __syncthreads();

    float q[PP];
#pragma unroll
    for (int i = 0; i < PS; i++)
#pragma unroll
        for (int j = 0; j < PS; j++)
            q[i * PS + j] = reg[INC + i][INC + j];

    for (int o = tid; o < NOFF; o += 256) {
        int oi = o / WSZ, oj = o % WSZ;
        float s = 0.f;
#pragma unroll
        for (int i = 0; i < PS; i++)
#pragma unroll
            for (int j = 0; j < PS; j++) {
                float d = reg[oi + i][oj + j] - q[i * PS + j];
                s += d * d;
            }
        dist[o] = (o == INC * WSZ + INC) ? -1.0f : s;   // self match sentinel
    }
    __syncthreads();

    if (tid >= 64) return;        // selection runs on wave 0 only
    const int lane = tid;

    float dv[UCAP];
#pragma unroll
    for (int u = 0; u < UCAP; u++) {
        int o = lane + (u << 6);
        dv[u] = (o < NOFF) ? dist[o] : FLT_MAX;
    }

    const int blk = gi * GDIM + gj;
    for (int sel = 0; sel < m; sel++) {
        float bv = dv[0]; int bo = lane;
#pragma unroll
        for (int u = 1; u < UCAP; u++) {
            int o = lane + (u << 6);
            if (dv[u] < bv) { bv = dv[u]; bo = o; }
        }
#pragma unroll
        for (int d = 1; d < 64; d <<= 1) {
            float ov = __shfl_xor(bv, d);
            int   oo = __shfl_xor(bo, d);
            if (ov < bv || (ov == bv && oo < bo)) { bv = ov; bo = oo; }
        }
        if (lane == 0) {
            int oi = bo / WSZ, oj = bo % WSZ;
            pos[blk * m + sel] = (oi + ST * gi) * XDIM + (oj + ST * gj);
        }
#pragma unroll
        for (int u = 0; u < UCAP; u++)
            if (bo == lane + (u << 6)) dv[u] = FLT_MAX;
    }
}

// ---------------- denoise + scatter: one workgroup per group ----------------
// M = Gram(S) (+ c*I if ADDC). Inversion: symmetric sweep operator on wave 0,
// column-per-lane in registers (A -> -A^{-1}), broadcast via v_readlane.
// theta = I - c*Minv; Xh = Y - c*(Minv Y); w_k = 1/rowsum(theta^2).
// SLAB path: accumulate (num, wsum) into a private 2x43x43 LDS tile
// (LDS atomics), then PLAIN coalesced stores to the per-group slab.
// Fallback (!SLAB): R5's global-atomic 49-plane scatter.
template<int M_, bool ADDC, bool SLAB>
__global__ __launch_bounds__(256) void denoise_scatter(
    const float* __restrict__ padY, const float* __restrict__ padS,
    const int* __restrict__ pos, const float* __restrict__ sigma_p,
    float* __restrict__ dst, float* __restrict__ Wacc)
{
    constexpr int MP = (M_ + 4) & ~3;        // Msh row stride (mult of 4): 56 / 20
    constexpr int SS = 52;                   // Ssh row stride (13*16B, zero-padded)
    constexpr int YS = 60;                   // Yt  row stride (15*16B)

    __shared__ __align__(16) float Ssh[M_ * SS];
    __shared__ __align__(16) float Yt [PP * YS];   // Yt[qq][k] = Y patch k, pixel qq
    __shared__ __align__(16) float Msh[M_ * MP];
    __shared__ float tile[SLAB ? 2 * TSZ : 1];
    __shared__ float wsh[M_];
    __shared__ int   posh[M_];

    const int tid = threadIdx.x;
    const int blk = blockIdx.x;
    const float sg = *sigma_p;
    const float c  = (float)PP * sg * sg;

    if (tid < M_) posh[tid] = pos[blk * M_ + tid];
    if (SLAB)
        for (int t = tid; t < 2 * TSZ; t += 256) tile[t] = 0.f;
    __syncthreads();

    // gather A: Ssh row-major (stride-1 LDS writes), cols 49..51 zeroed
    for (int t = tid; t < M_ * SS; t += 256) {
        int k = t / SS, qq = t - k * SS;
        float v = 0.f;
        if (qq < PP) {
            int p_ = posh[k];
            int a = p_ / XDIM, b = p_ - (p_ / XDIM) * XDIM;
            v = padS[(a + qq / PS) * PDIM + (b + qq % PS)];
        }
        Ssh[t] = v;
    }
    // gather B: Yt transposed (k fastest -> stride-1 LDS writes)
    for (int t = tid; t < PP * M_; t += 256) {
        int qq = t / M_, k = t - qq * M_;
        int p_ = posh[k];
        int a = p_ / XDIM, b = p_ - (p_ / XDIM) * XDIM;
        Yt[qq * YS + k] = padY[(a + qq / PS) * PDIM + (b + qq % PS)];
    }
    __syncthreads();

    // Gram, lower triangle only, float4 over q
    for (int t = tid; t < M_ * M_; t += 256) {
        int i = t / M_, j = t - i * M_;
        if (j > i) continue;
        const float4* Si = (const float4*)&Ssh[i * SS];
        const float4* Sj = (const float4*)&Ssh[j * SS];
        float acc = 0.f;
#pragma unroll
        for (int cch = 0; cch < SS / 4; cch++) {
            float4 a4 = Si[cch], b4 = Sj[cch];
            acc += a4.x * b4.x + a4.y * b4.y + a4.z * b4.z + a4.w * b4.w;
        }
        if (ADDC && i == j) acc += c;
        Msh[i * MP + j] = acc;
    }
    __syncthreads();

    // ---- symmetric sweep inversion on wave 0 (register columns) ----
    if (tid < 64) {
        const int j = (tid < M_) ? tid : (M_ - 1);   // clamp extra lanes
        float col[M_];
#pragma unroll
        for (int i = 0; i < M_; i++)
            col[i] = Msh[(i >= j) ? (i * MP + j) : (j * MP + i)];

#pragma unroll
        for (int k = 0; k < M_; k++) {
            float d = __int_as_float(__builtin_amdgcn_readlane(__float_as_int(col[k]), k));
            d = (fabsf(d) > 1e-30f) ? d : 1e-30f;
            float dinv = 1.0f / d;
            float cks = col[k];
            float f  = (j == k) ? (1.0f - dinv) : (cks * dinv);
            float fn = -f;
#pragma unroll
            for (int i = 0; i < M_; i++) {
                if (i == k) continue;
                float aik = __int_as_float(__builtin_amdgcn_readlane(__float_as_int(cks), i));
                col[i] = fmaf(aik, fn, col[i]);
            }
            col[k] = (j == k) ? (-dinv) : (cks * dinv);
        }
        // now col = column j of -M^{-1}
        if (tid < M_) {
            float s = 0.f;
#pragma unroll
            for (int i = 0; i < M_; i++) {
                float th = fmaf(c, col[i], (i == j) ? 1.f : 0.f);  // I - c*Minv
                s = fmaf(th, th, s);
            }
            wsh[j] = 1.0f / s;
#pragma unroll
            for (int i = 0; i < M_; i++)
                Msh[i * MP + j] = -col[i];                          // Minv (full)
        }
    }
    __syncthreads();

    // ---- Z = Minv*Y fused with weighted scatter ----
    const int r0 = ST * (blk >> 6), c0 = ST * (blk & (GDIM - 1));
    for (int t = tid; t < M_ * PP; t += 256) {
        int k = t / PP, qq = t - k * PP;
        const float4* Mi = (const float4*)&Msh[k * MP];
        const float4* Yq = (const float4*)&Yt [qq * YS];
        float z = 0.f;
#pragma unroll
        for (int cch = 0; cch < M_ / 4; cch++) {
            float4 a4 = Mi[cch], b4 = Yq[cch];
            z += a4.x * b4.x + a4.y * b4.y + a4.z * b4.z + a4.w * b4.w;
        }
#pragma unroll
        for (int jj = (M_ / 4) * 4; jj < M_; jj++)
            z += Msh[k * MP + jj] * Yt[qq * YS + jj];
        float xh = Yt[qq * YS + k] - c * z;
        float wk = wsh[k];
        int p_ = posh[k];
        if (SLAB) {
            int a = p_ / XDIM, b = p_ - (p_ / XDIM) * XDIM;
            int loc = (a - r0 + qq / PS) * TDIM + (b - c0 + qq % PS);
            atomicAdd(&tile[loc], xh * wk);
            atomicAdd(&tile[TSZ + loc], wk);
        } else {
            atomicAdd(&dst[qq * LTOT + p_], xh * wk);
        }
    }
    if (SLAB) {
        __syncthreads();
        float* g = dst + (size_t)blk * SLABSTRIDE;
        for (int t = tid; t < 2 * TSZ; t += 256) g[t] = tile[t];
    } else {
        for (int t = tid; t < M_; t += 256)
            atomicAdd(&Wacc[posh[t]], wsh[t]);
    }
}

// ---------------- slab fold: gather <=11x11 group tiles, divide, crop -------
__global__ void fold_slab(const float* __restrict__ slab, float* __restrict__ out)
{
    int idx = blockIdx.x * 256 + threadIdx.x;
    if (idx >= IMG * IMG) return;
    int y = (idx >> 8) + PADR, x = (idx & 255) + PADR;   // padded coords
    int qy = y >> 2, ry = y & 3;
    int qx = x >> 2, rx = x & 3;
    float num = 0.f, den = 0.f;
    for (int di = 0; di < 11; di++) {
        int gi = qy - di;
        int li = 4 * di + ry;
        if ((unsigned)gi > (unsigned)(GDIM - 1) || li >= TDIM) continue;
        for (int dj = 0; dj < 11; dj++) {
            int gj = qx - dj;
            int lj = 4 * dj + rx;
            if ((unsigned)gj > (unsigned)(GDIM - 1) || lj >= TDIM) continue;
            const float* s = slab + (size_t)((gi << 6) + gj) * SLABSTRIDE + li * TDIM + lj;
            num += s[0];
            den += s[TSZ];
        }
    }
    out[idx] = num / den;
}

// ---------------- fallback fold (49-tap over planes) + normalize + crop -----
__global__ void fold_norm(const float* __restrict__ Xsum, const float* __restrict__ Wacc,
                          float* __restrict__ out)
{
    int idx = blockIdx.x * 256 + threadIdx.x;
    if (idx >= IMG * IMG) return;
    int y0 = idx / IMG, x0 = idx % IMG;
    int y = y0 + PADR, x = x0 + PADR;
    float num = 0.f, den = 0.f;
#pragma unroll
    for (int i = 0; i < PS; i++)
#pragma unroll
        for (int j = 0; j < PS; j++) {
            int a = y - i, b = x - j;
            num += Xsum[(i * PS + j) * LTOT + a * XDIM + b];
            den += Wacc[a * XDIM + b];
        }
    out[idx] = num / den;
}

extern "C" void kernel_launch(void* const* d_in, const int* in_sizes, int n_in,
                              void* d_out, int out_size, void* d_ws, size_t ws_size,
                              hipStream_t stream)
{
    const float* input = (const float*)d_in[0];
    const float* sigma = (const float*)d_in[1];
    float* out = (float*)d_out;

    char* ws = (char*)d_ws;
    float* padY = (float*)ws; ws += (size_t)PDIM * PDIM * 4;
    float* padX = (float*)ws; ws += (size_t)PDIM * PDIM * 4;
    float* den1 = (float*)ws; ws += (size_t)IMG * IMG * 4;
    int*   pos  = (int*)ws;   ws += (size_t)NBLK * MM2 * 4;
    size_t head = (size_t)(ws - (char*)d_ws);
    size_t slabBytes = (size_t)NBLK * SLABSTRIDE * 4;

    const int padBlocks = (PDIM * PDIM + 255) / 256;
    const int imgBlocks = (IMG * IMG + 255) / 256;

    if (ws_size >= head + slabBytes) {
        // ---- slab path: zero global atomics ----
        float* slab = (float*)ws;

        pad_reflect<<<padBlocks, 256, 0, stream>>>(input, padY);
        block_match<<<dim3(GDIM, GDIM), 256, 0, stream>>>(padY, pos, MM1);
        denoise_scatter<MM1, false, true><<<NBLK, 256, 0, stream>>>(padY, padY, pos, sigma,
                                                                    slab, nullptr);
        fold_slab<<<imgBlocks, 256, 0, stream>>>(slab, den1);

        pad_reflect<<<padBlocks, 256, 0, stream>>>(den1, padX);
        block_match<<<dim3(GDIM, GDIM), 256, 0, stream>>>(padX, pos, MM2);
        denoise_scatter<MM2, true, true><<<NBLK, 256, 0, stream>>>(padY, padX, pos, sigma,
                                                                   slab, nullptr);
        fold_slab<<<imgBlocks, 256, 0, stream>>>(slab, out);
    } else {
        // ---- fallback: R5 global-atomic path ----
        float* Xsum = (float*)ws; ws += (size_t)PP * LTOT * 4;
        float* Wacc = (float*)ws;

        hipMemsetAsync(Xsum, 0, (size_t)PP * LTOT * 4, stream);
        hipMemsetAsync(Wacc, 0, (size_t)LTOT * 4, stream);
        pad_reflect<<<padBlocks, 256, 0, stream>>>(input, padY);
        block_match<<<dim3(GDIM, GDIM), 256, 0, stream>>>(padY, pos, MM1);
        denoise_scatter<MM1, false, false><<<NBLK, 256, 0, stream>>>(padY, padY, pos, sigma,
                                                                     Xsum, Wacc);
        fold_norm<<<imgBlocks, 256, 0, stream>>>(Xsum, Wacc, den1);

        pad_reflect<<<padBlocks, 256, 0, stream>>>(den1, padX);
        hipMemsetAsync(Xsum, 0, (size_t)PP * LTOT * 4, stream);
        hipMemsetAsync(Wacc, 0, (size_t)LTOT * 4, stream);
        block_match<<<dim3(GDIM, GDIM), 256, 0, stream>>>(padX, pos, MM2);
        denoise_scatter<MM2, true, false><<<NBLK, 256, 0, stream>>>(padY, padX, pos, sigma,
                                                                    Xsum, Wacc);
        fold_norm<<<imgBlocks, 256, 0, stream>>>(Xsum, Wacc, out);
    }
}

// Round 7
// 1096.152 us; speedup vs baseline: 1.3897x; 1.1910x over previous
//
#include <hip/hip_runtime.h>
#include <math.h>
#include <float.h>

// ---- problem constants (N=1, C=1, 256x256, sigma scalar) ----
constexpr int IMG  = 256;            // H = W
constexpr int PADR = 21;             // p//2 + w//2 = 3 + 18
constexpr int PDIM = IMG + 2*PADR;   // 298
constexpr int XDIM = PDIM - 7 + 1;   // 292  (unfold spatial dim)
constexpr int LTOT = XDIM * XDIM;    // 85264
constexpr int WSZ  = 37;             // search window
constexpr int INC  = 18;             // WSZ/2
constexpr int ST   = 4;              // stride
constexpr int GDIM = 64;             // query grid per dim (256/4)
constexpr int NBLK = GDIM * GDIM;    // 4096
constexpr int PS   = 7;              // patch size
constexpr int PP   = 49;             // patch pixels
constexpr int MM1  = 18;
constexpr int MM2  = 55;
constexpr int RG   = 43;             // search region = 2*INC + PS
constexpr int NOFF = WSZ * WSZ;      // 1369
constexpr int UCAP = (NOFF + 63) / 64;  // 22 dist values cached per lane
constexpr int TDIM = 43;             // per-group output footprint (37 + 7 - 1)
constexpr int TSZ  = TDIM * TDIM;    // 1849
constexpr int SLABSTRIDE = 2 * TSZ;  // num + weight channels per group

// ---------------- reflect pad: src (IMG x IMG) -> dst (PDIM x PDIM) ----------
__global__ void pad_reflect(const float* __restrict__ src, float* __restrict__ dst)
{
    int idx = blockIdx.x * 256 + threadIdx.x;
    if (idx >= PDIM * PDIM) return;
    int y = idx / PDIM, x = idx % PDIM;
    int oy = y - PADR; oy = (oy < 0) ? -oy : ((oy >= IMG) ? 2*(IMG-1) - oy : oy);
    int ox = x - PADR; ox = (ox < 0) ? -ox : ((ox >= IMG) ? 2*(IMG-1) - ox : ox);
    dst[idx] = src[oy * IMG + ox];
}

// ---------------- block matching: one workgroup per query block -------------
__global__ __launch_bounds__(256) void block_match(const float* __restrict__ pad,
                                                   int* __restrict__ pos, int m)
{
    __shared__ float reg[RG][RG + 1];
    __shared__ float dist[NOFF];

    const int gi = blockIdx.y, gj = blockIdx.x;
    const int tid = threadIdx.x;
    const int r0 = ST * gi, c0 = ST * gj;

    for (int t = tid; t < RG * RG; t += 256) {
        int r = t / RG, c = t % RG;
        reg[r][c] = pad[(r0 + r) * PDIM + (c0 + c)];
    }
    __syncthreads();

    float q[PP];
#pragma unroll
    for (int i = 0; i < PS; i++)
#pragma unroll
        for (int j = 0; j < PS; j++)
            q[i * PS + j] = reg[INC + i][INC + j];

    for (int o = tid; o < NOFF; o += 256) {
        int oi = o / WSZ, oj = o % WSZ;
        float s = 0.f;
#pragma unroll
        for (int i = 0; i < PS; i++)
#pragma unroll
            for (int j = 0; j < PS; j++) {
                float d = reg[oi + i][oj + j] - q[i * PS + j];
                s += d * d;
            }
        dist[o] = (o == INC * WSZ + INC) ? -1.0f : s;   // self match sentinel
    }
    __syncthreads();

    if (tid >= 64) return;        // selection runs on wave 0 only
    const int lane = tid;

    float dv[UCAP];
#pragma unroll
    for (int u = 0; u < UCAP; u++) {
        int o = lane + (u << 6);
        dv[u] = (o < NOFF) ? dist[o] : FLT_MAX;
    }

    const int blk = gi * GDIM + gj;
    for (int sel = 0; sel < m; sel++) {
        float bv = dv[0]; int bo = lane;
#pragma unroll
        for (int u = 1; u < UCAP; u++) {
            int o = lane + (u << 6);
            if (dv[u] < bv) { bv = dv[u]; bo = o; }
        }
#pragma unroll
        for (int d = 1; d < 64; d <<= 1) {
            float ov = __shfl_xor(bv, d);
            int   oo = __shfl_xor(bo, d);
            if (ov < bv || (ov == bv && oo < bo)) { bv = ov; bo = oo; }
        }
        if (lane == 0) {
            int oi = bo / WSZ, oj = bo % WSZ;
            pos[blk * m + sel] = (oi + ST * gi) * XDIM + (oj + ST * gj);
        }
#pragma unroll
        for (int u = 0; u < UCAP; u++)
            if (bo == lane + (u << 6)) dv[u] = FLT_MAX;
    }
}

// ---------------- denoise + scatter: one workgroup per group ----------------
// M = Gram(S) (+ c*I if ADDC). Inversion: symmetric sweep, column-per-lane in
// wave-0 registers; RUNTIME k-loop (compact code, I-cache friendly) with the
// pivot column broadcast through a tiny LDS array. Waves 1-3 gather Yt and
// zero the tile concurrently with the sweep.
// theta = I - c*Minv; Xh = Y - c*(Minv Y); w_k = 1/rowsum(theta^2).
// SLAB path: accumulate (num,wsum) into a private 2x43x43 LDS tile (LDS
// atomics) then plain coalesced stores to the per-group slab.
template<int M_, bool ADDC, bool SLAB>
__global__ __launch_bounds__(256) void denoise_scatter(
    const float* __restrict__ padY, const float* __restrict__ padS,
    const int* __restrict__ pos, const float* __restrict__ sigma_p,
    float* __restrict__ dst, float* __restrict__ Wacc)
{
    constexpr int MP = (M_ + 4) & ~3;        // Msh row stride (mult of 4): 56 / 20
    constexpr int SS = 52;                   // Ssh row stride (13*16B, zero-padded)
    constexpr int YS = 60;                   // Yt  row stride (15*16B)
    constexpr int UN = (2 * TSZ > M_ * SS) ? 2 * TSZ : M_ * SS;   // Ssh ∪ tile

    __shared__ __align__(16) float Yt [PP * YS];   // Yt[qq][k], cols M_..MP-1 zero
    __shared__ __align__(16) float Msh[M_ * MP];   // Gram -> Minv, pad cols zero
    __shared__ __align__(16) float SorT[UN];       // Ssh (gather/Gram) then tile
    __shared__ float pcol[M_];
    __shared__ float wsh[M_];
    __shared__ int   posh[M_];

    float* Ssh  = SorT;
    float* tile = SorT;

    const int tid = threadIdx.x;
    const int blk = blockIdx.x;
    const float sg = *sigma_p;
    const float c  = (float)PP * sg * sg;

    if (tid < M_) posh[tid] = pos[blk * M_ + tid];
    __syncthreads();

    // gather S: Ssh row-major (stride-1 LDS writes), cols 49..51 zeroed
    for (int t = tid; t < M_ * SS; t += 256) {
        int k = t / SS, qq = t - (t / SS) * SS;
        float v = 0.f;
        if (qq < PP) {
            int p_ = posh[k];
            int a = p_ / XDIM, b = p_ - (p_ / XDIM) * XDIM;
            v = padS[(a + qq / PS) * PDIM + (b + qq % PS)];
        }
        Ssh[t] = v;
    }
    __syncthreads();

    // Gram, lower triangle only, float4 over q
    for (int t = tid; t < M_ * M_; t += 256) {
        int i = t / M_, j = t - (t / M_) * M_;
        if (j > i) continue;
        const float4* Si = (const float4*)&Ssh[i * SS];
        const float4* Sj = (const float4*)&Ssh[j * SS];
        float acc = 0.f;
#pragma unroll
        for (int cch = 0; cch < SS / 4; cch++) {
            float4 a4 = Si[cch], b4 = Sj[cch];
            acc += a4.x * b4.x + a4.y * b4.y + a4.z * b4.z + a4.w * b4.w;
        }
        if (ADDC && i == j) acc += c;
        Msh[i * MP + j] = acc;
    }
    __syncthreads();

    // ---- wave0: sweep inversion (runtime k loop, compact code) ----
    // ---- waves1-3: gather Yt + zero tile, overlapped with the sweep ----
    if (tid < 64) {
        const int j = (tid < M_) ? tid : (M_ - 1);   // clamp extra lanes
        float col[M_];
#pragma unroll
        for (int i = 0; i < M_; i++)
            col[i] = Msh[(i >= j) ? (i * MP + j) : (j * MP + i)];

#pragma unroll 1
        for (int k = 0; k < M_; k++) {
            // lane k publishes the pivot column (column k == its registers)
            if (tid == k) {
#pragma unroll
                for (int i = 0; i < M_; i++) pcol[i] = col[i];
            }
            float piv = pcol[j];          // A[k][j]  (same-wave DS ordering)
            float d   = pcol[k];          // pivot diagonal (broadcast read)
            d = (fabsf(d) > 1e-30f) ? d : 1e-30f;
            float dinv = 1.0f / d;
            bool  isk  = (j == k);
            float f    = isk ? (1.0f - dinv) : (piv * dinv);
            float fix  = isk ? (-dinv)       : (piv * dinv);
            float negf = -f;
#pragma unroll
            for (int i = 0; i < M_; i++) {
                float b   = __int_as_float(
                    __builtin_amdgcn_readlane(__float_as_int(col[i]), k));
                float upd = fmaf(b, negf, col[i]);
                col[i] = (i == k) ? fix : upd;
            }
        }
        // col = column j of -M^{-1}
        if (tid < M_) {
            float s = 0.f;
#pragma unroll
            for (int i = 0; i < M_; i++) {
                float th = fmaf(c, col[i], (i == j) ? 1.f : 0.f);  // I - c*Minv
                s = fmaf(th, th, s);
            }
            wsh[j] = 1.0f / s;
#pragma unroll
            for (int i = 0; i < M_; i++)
                Msh[i * MP + j] = -col[i];                          // Minv
        } else if (tid < MP) {
#pragma unroll
            for (int i = 0; i < M_; i++)
                Msh[i * MP + tid] = 0.f;                            // zero pad cols
        }
    } else {
        const int t0 = tid - 64;
        // gather Yt transposed, cols M_..MP-1 zeroed (for padded float4 dots)
        for (int t = t0; t < PP * MP; t += 192) {
            int qq = t / MP, k = t - (t / MP) * MP;
            float v = 0.f;
            if (k < M_) {
                int p_ = posh[k];
                int a = p_ / XDIM, b = p_ - (p_ / XDIM) * XDIM;
                v = padY[(a + qq / PS) * PDIM + (b + qq % PS)];
            }
            Yt[qq * YS + k] = v;
        }
        if (SLAB)
            for (int t = t0; t < 2 * TSZ; t += 192) tile[t] = 0.f;
    }
    __syncthreads();

    // ---- Z = Minv*Y, 2x2 register-tiled, fused weighted scatter ----
    constexpr int KP = (M_ + 1) / 2;
    constexpr int QP = (PP + 1) / 2;
    const int r0 = ST * (blk >> 6), c0 = ST * (blk & (GDIM - 1));
    for (int t = tid; t < KP * QP; t += 256) {
        int kp = t / QP, qp = t - (t / QP) * QP;
        int k0 = kp * 2, k1 = k0 + 1;
        int qq0 = qp * 2, qq1 = qq0 + 1;
        bool k1v = (k1 < M_), q1v = (qq1 < PP);
        int k1c  = k1v ? k1 : k0;
        int qq1c = q1v ? qq1 : qq0;
        const float4* G0 = (const float4*)&Msh[k0  * MP];
        const float4* G1 = (const float4*)&Msh[k1c * MP];
        const float4* Y0 = (const float4*)&Yt [qq0  * YS];
        const float4* Y1 = (const float4*)&Yt [qq1c * YS];
        float z00 = 0.f, z01 = 0.f, z10 = 0.f, z11 = 0.f;
#pragma unroll
        for (int cch = 0; cch < MP / 4; cch++) {
            float4 g0 = G0[cch], g1 = G1[cch], y0 = Y0[cch], y1 = Y1[cch];
            z00 += g0.x*y0.x + g0.y*y0.y + g0.z*y0.z + g0.w*y0.w;
            z01 += g0.x*y1.x + g0.y*y1.y + g0.z*y1.z + g0.w*y1.w;
            z10 += g1.x*y0.x + g1.y*y0.y + g1.z*y0.z + g1.w*y0.w;
            z11 += g1.x*y1.x + g1.y*y1.y + g1.z*y1.z + g1.w*y1.w;
        }
        float w0 = wsh[k0], w1 = k1v ? wsh[k1] : 0.f;
        int p0 = posh[k0], p1 = posh[k1c];
        float xh00 = (Yt[qq0  * YS + k0 ] - c * z00) * w0;
        float xh01 = (Yt[qq1c * YS + k0 ] - c * z01) * w0;
        float xh10 = (Yt[qq0  * YS + k1c] - c * z10) * w1;
        float xh11 = (Yt[qq1c * YS + k1c] - c * z11) * w1;
        int a0 = p0 / XDIM, b0 = p0 - (p0 / XDIM) * XDIM;
        int a1 = p1 / XDIM, b1 = p1 - (p1 / XDIM) * XDIM;
        int i0 = qq0 / PS, j0 = qq0 - i0 * PS;
        int i1 = qq1 / PS, j1 = qq1 - i1 * PS;   // qq1 may be PP -> guarded
        if (SLAB) {
            int u0 = a0 - r0, v0 = b0 - c0, u1 = a1 - r0, v1 = b1 - c0;
            int l00 = (u0 + i0) * TDIM + v0 + j0;
            int l10 = (u1 + i0) * TDIM + v1 + j0;
            atomicAdd(&tile[l00], xh00); atomicAdd(&tile[TSZ + l00], w0);
            atomicAdd(&tile[l10], xh10); atomicAdd(&tile[TSZ + l10], w1);
            if (q1v) {
                int l01 = (u0 + i1) * TDIM + v0 + j1;
                int l11 = (u1 + i1) * TDIM + v1 + j1;
                atomicAdd(&tile[l01], xh01); atomicAdd(&tile[TSZ + l01], w0);
                atomicAdd(&tile[l11], xh11); atomicAdd(&tile[TSZ + l11], w1);
            }
        } else {
            atomicAdd(&dst[qq0 * LTOT + p0], xh00);
            if (q1v) atomicAdd(&dst[qq1 * LTOT + p0], xh01);
            if (k1v) {
                atomicAdd(&dst[qq0 * LTOT + p1], xh10);
                if (q1v) atomicAdd(&dst[qq1 * LTOT + p1], xh11);
            }
        }
    }
    if (SLAB) {
        __syncthreads();
        float* g = dst + (size_t)blk * SLABSTRIDE;
        for (int t = tid; t < 2 * TSZ; t += 256) g[t] = tile[t];
    } else {
        for (int t = tid; t < M_; t += 256)
            atomicAdd(&Wacc[posh[t]], wsh[t]);
    }
}

// ---------------- slab fold: gather <=11x11 group tiles, divide, crop -------
__global__ void fold_slab(const float* __restrict__ slab, float* __restrict__ out)
{
    int idx = blockIdx.x * 256 + threadIdx.x;
    if (idx >= IMG * IMG) return;
    int y = (idx >> 8) + PADR, x = (idx & 255) + PADR;   // padded coords
    int qy = y >> 2, ry = y & 3;
    int qx = x >> 2, rx = x & 3;
    float num = 0.f, den = 0.f;
    for (int di = 0; di < 11; di++) {
        int gi = qy - di;
        int li = 4 * di + ry;
        if ((unsigned)gi > (unsigned)(GDIM - 1) || li >= TDIM) continue;
        for (int dj = 0; dj < 11; dj++) {
            int gj = qx - dj;
            int lj = 4 * dj + rx;
            if ((unsigned)gj > (unsigned)(GDIM - 1) || lj >= TDIM) continue;
            const float* s = slab + (size_t)((gi << 6) + gj) * SLABSTRIDE + li * TDIM + lj;
            num += s[0];
            den += s[TSZ];
        }
    }
    out[idx] = num / den;
}

// ---------------- fallback fold (49-tap over planes) + normalize + crop -----
__global__ void fold_norm(const float* __restrict__ Xsum, const float* __restrict__ Wacc,
                          float* __restrict__ out)
{
    int idx = blockIdx.x * 256 + threadIdx.x;
    if (idx >= IMG * IMG) return;
    int y0 = idx / IMG, x0 = idx % IMG;
    int y = y0 + PADR, x = x0 + PADR;
    float num = 0.f, den = 0.f;
#pragma unroll
    for (int i = 0; i < PS; i++)
#pragma unroll
        for (int j = 0; j < PS; j++) {
            int a = y - i, b = x - j;
            num += Xsum[(i * PS + j) * LTOT + a * XDIM + b];
            den += Wacc[a * XDIM + b];
        }
    out[idx] = num / den;
}

extern "C" void kernel_launch(void* const* d_in, const int* in_sizes, int n_in,
                              void* d_out, int out_size, void* d_ws, size_t ws_size,
                              hipStream_t stream)
{
    const float* input = (const float*)d_in[0];
    const float* sigma = (const float*)d_in[1];
    float* out = (float*)d_out;

    char* ws = (char*)d_ws;
    float* padY = (float*)ws; ws += (size_t)PDIM * PDIM * 4;
    float* padX = (float*)ws; ws += (size_t)PDIM * PDIM * 4;
    float* den1 = (float*)ws; ws += (size_t)IMG * IMG * 4;
    int*   pos  = (int*)ws;   ws += (size_t)NBLK * MM2 * 4;
    size_t head = (size_t)(ws - (char*)d_ws);
    size_t slabBytes = (size_t)NBLK * SLABSTRIDE * 4;

    const int padBlocks = (PDIM * PDIM + 255) / 256;
    const int imgBlocks = (IMG * IMG + 255) / 256;

    if (ws_size >= head + slabBytes) {
        // ---- slab path: zero global atomics ----
        float* slab = (float*)ws;

        pad_reflect<<<padBlocks, 256, 0, stream>>>(input, padY);
        block_match<<<dim3(GDIM, GDIM), 256, 0, stream>>>(padY, pos, MM1);
        denoise_scatter<MM1, false, true><<<NBLK, 256, 0, stream>>>(padY, padY, pos, sigma,
                                                                    slab, nullptr);
        fold_slab<<<imgBlocks, 256, 0, stream>>>(slab, den1);

        pad_reflect<<<padBlocks, 256, 0, stream>>>(den1, padX);
        block_match<<<dim3(GDIM, GDIM), 256, 0, stream>>>(padX, pos, MM2);
        denoise_scatter<MM2, true, true><<<NBLK, 256, 0, stream>>>(padY, padX, pos, sigma,
                                                                   slab, nullptr);
        fold_slab<<<imgBlocks, 256, 0, stream>>>(slab, out);
    } else {
        // ---- fallback: global-atomic 49-plane path ----
        float* Xsum = (float*)ws; ws += (size_t)PP * LTOT * 4;
        float* Wacc = (float*)ws;

        hipMemsetAsync(Xsum, 0, (size_t)PP * LTOT * 4, stream);
        hipMemsetAsync(Wacc, 0, (size_t)LTOT * 4, stream);
        pad_reflect<<<padBlocks, 256, 0, stream>>>(input, padY);
        block_match<<<dim3(GDIM, GDIM), 256, 0, stream>>>(padY, pos, MM1);
        denoise_scatter<MM1, false, false><<<NBLK, 256, 0, stream>>>(padY, padY, pos, sigma,
                                                                     Xsum, Wacc);
        fold_norm<<<imgBlocks, 256, 0, stream>>>(Xsum, Wacc, den1);

        pad_reflect<<<padBlocks, 256, 0, stream>>>(den1, padX);
        hipMemsetAsync(Xsum, 0, (size_t)PP * LTOT * 4, stream);
        hipMemsetAsync(Wacc, 0, (size_t)LTOT * 4, stream);
        block_match<<<dim3(GDIM, GDIM), 256, 0, stream>>>(padX, pos, MM2);
        denoise_scatter<MM2, true, false><<<NBLK, 256, 0, stream>>>(padY, padX, pos, sigma,
                                                                    Xsum, Wacc);
        fold_norm<<<imgBlocks, 256, 0, stream>>>(Xsum, Wacc, out);
    }
}